// Round 1
// baseline (605.797 us; speedup 1.0000x reference)
//
#include <hip/hip_runtime.h>
#include <stdint.h>

typedef __bf16 bf16x8_t __attribute__((ext_vector_type(8)));
typedef float f32x4_t __attribute__((ext_vector_type(4)));

static __device__ __forceinline__ unsigned short f2bf(float f) {
  union { float f; unsigned u; } a;
  a.f = f;
  unsigned r = a.u + 0x7fffu + ((a.u >> 16) & 1u);
  return (unsigned short)(r >> 16);
}

// ---------- 1. fp32 -> bf16 elementwise ----------
__global__ void cvt_bf16_kernel(const float* __restrict__ in, unsigned short* __restrict__ out) {
  long i = ((long)blockIdx.x * blockDim.x + threadIdx.x) * 4;
  float4 v = *(const float4*)(in + i);
  ushort4 o;
  o.x = f2bf(v.x);
  o.y = f2bf(v.y);
  o.z = f2bf(v.z);
  o.w = f2bf(v.w);
  *(ushort4*)(out + i) = o;
}

// ---------- 2. fp32 [R][C] (row stride ld) -> bf16 [C][R] (row stride dld) ----------
__global__ void transpose_f32_bf16(const float* __restrict__ src, unsigned short* __restrict__ dst,
                                   int ld, int dld, long sbs, long dbs) {
  __shared__ float tile[64][65];
  src += (long)blockIdx.z * sbs;
  dst += (long)blockIdx.z * dbs;
  const int c0 = blockIdx.x * 64, r0 = blockIdx.y * 64;
  const int tx = threadIdx.x, ty = threadIdx.y;
#pragma unroll
  for (int j = 0; j < 64; j += 4)
    tile[ty + j][tx] = src[(long)(r0 + ty + j) * ld + (c0 + tx)];
  __syncthreads();
#pragma unroll
  for (int j = 0; j < 64; j += 4)
    dst[(long)(c0 + ty + j) * dld + (r0 + tx)] = f2bf(tile[tx][ty + j]);
}

// ---------- 3. GEMM: C[M][N] = A[M][K] * Bt[N][K]^T  (bf16 in, fp32 out) ----------
// 128x128 tile, BK=32, 4 waves (each 64x64), global_load_lds staging (m97 structure).
__global__ __launch_bounds__(256) void gemm_bt(const unsigned short* __restrict__ A,
                                               const unsigned short* __restrict__ Bt,
                                               float* __restrict__ C,
                                               int M, int N, int K) {
  __shared__ unsigned short As[128 * 32];
  __shared__ unsigned short Bs[128 * 32];
  const int tid = threadIdx.x;
  const int wid = tid >> 6, lane = tid & 63;
  const int r16 = lane & 15, g = lane >> 4;
  const long bm = (long)blockIdx.y * 128;
  const long bn = (long)blockIdx.x * 128;
  const int wr = (wid >> 1) * 64, wc = (wid & 1) * 64;
  f32x4_t acc[4][4];
#pragma unroll
  for (int i = 0; i < 4; i++)
#pragma unroll
    for (int j = 0; j < 4; j++) acc[i][j] = (f32x4_t){0.f, 0.f, 0.f, 0.f};

  for (int kt = 0; kt < K; kt += 32) {
#pragma unroll
    for (int i = 0; i < 2; i++) {
      const int chunk = (i * 4 + wid) * 64 + lane;  // 512 chunks of 16B per tile
      const int row = chunk >> 2, col = (chunk & 3) * 8;
      __builtin_amdgcn_global_load_lds(
          (const __attribute__((address_space(1))) void*)(A + (bm + row) * K + kt + col),
          (__attribute__((address_space(3))) void*)(As + chunk * 8), 16, 0, 0);
      __builtin_amdgcn_global_load_lds(
          (const __attribute__((address_space(1))) void*)(Bt + (bn + row) * K + kt + col),
          (__attribute__((address_space(3))) void*)(Bs + chunk * 8), 16, 0, 0);
    }
    __syncthreads();
    bf16x8_t af[4], bfr[4];
#pragma unroll
    for (int mi = 0; mi < 4; mi++)
      af[mi] = *(const bf16x8_t*)(As + (wr + mi * 16 + r16) * 32 + g * 8);
#pragma unroll
    for (int ni = 0; ni < 4; ni++)
      bfr[ni] = *(const bf16x8_t*)(Bs + (wc + ni * 16 + r16) * 32 + g * 8);
#pragma unroll
    for (int mi = 0; mi < 4; mi++)
#pragma unroll
      for (int ni = 0; ni < 4; ni++)
        acc[mi][ni] = __builtin_amdgcn_mfma_f32_16x16x32_bf16(af[mi], bfr[ni], acc[mi][ni], 0, 0, 0);
    __syncthreads();
  }
#pragma unroll
  for (int mi = 0; mi < 4; mi++)
#pragma unroll
    for (int ni = 0; ni < 4; ni++) {
      const long rowb = bm + wr + mi * 16 + 4 * g;
      const long colb = bn + wc + ni * 16 + r16;
#pragma unroll
      for (int j = 0; j < 4; j++)
        C[(rowb + j) * N + colb] = acc[mi][ni][j];
    }
}

// ---------- 4. RoPE + scale fold + layout ----------
// qkv fp32 [B*T][2304] -> qr bf16 (B,H,T,128) scaled by 1/128, kr bf16 (B,T,128)
__global__ void rope_kernel(const float* __restrict__ qkv,
                            const float* __restrict__ sinp,
                            const float* __restrict__ cosp,
                            unsigned short* __restrict__ qr,
                            unsigned short* __restrict__ kr) {
  const int row = blockIdx.x;  // b*2048 + t
  const int b = row >> 11, t = row & 2047;
  const float* src = qkv + (long)row * 2304;
  const int tid = threadIdx.x;
  const int d = tid & 127;
  const int dp = (d + 64) & 127;
  const float c = cosp[t * 128 + d];
  const float s = sinp[t * 128 + d];
  const float sgn = (d < 64) ? -1.f : 1.f;
  for (int h = (tid >> 7); h < 16; h += 2) {
    const float x0 = src[h * 128 + d];
    const float xp = src[h * 128 + dp];
    qr[((long)((b * 16 + h) * 2048 + t)) * 128 + d] = f2bf((x0 * c + sgn * xp * s) * 0.0078125f);
  }
  if (tid < 128) {
    const float x0 = src[2048 + d];
    const float xp = src[2048 + dp];
    kr[((long)(b * 2048 + t)) * 128 + d] = f2bf(x0 * c + sgn * xp * s);
  }
}

// ---------- 5. causal MQA flash attention ----------
// Each wave owns 16 q-rows; swapped QK^T (S^T = mfma(K,Q)) so lane owns q-row (lane&15).
// P redistributed to PV A-frag via per-wave swizzled LDS tile. KV read direct from L2.
__global__ __launch_bounds__(256) void mqa_attn(const unsigned short* __restrict__ qr,
                                                const unsigned short* __restrict__ kr,
                                                const unsigned short* __restrict__ vT,
                                                unsigned short* __restrict__ ao) {
  __shared__ unsigned short plds[4][512];  // per-wave 16x32 bf16 P tile
  const int tile = blockIdx.x, h = blockIdx.y, b = blockIdx.z;
  const int wid = threadIdx.x >> 6, lane = threadIdx.x & 63;
  const int r = lane & 15, g = lane >> 4;
  const int q0 = tile * 64 + wid * 16;
  const int swz = ((r >> 1) & 3) << 3;  // XOR-swizzle (byte bits 4-5) to spread rows
  unsigned short* pw = &plds[wid][0];

  bf16x8_t qf[4];
  const unsigned short* qp = qr + ((long)((b * 16 + h) * 2048 + q0 + r)) * 128 + g * 8;
#pragma unroll
  for (int c = 0; c < 4; c++) qf[c] = *(const bf16x8_t*)(qp + c * 32);

  f32x4_t o[8];
#pragma unroll
  for (int i = 0; i < 8; i++) o[i] = (f32x4_t){0.f, 0.f, 0.f, 0.f};
  float m = -1e30f, lsum = 0.f;

  const unsigned short* kb = kr + (long)b * 2048 * 128 + g * 8;
  const unsigned short* vb = vT + (long)b * 128 * 2048;
  const int nblk = (q0 + 15) / 32 + 1;

  for (int blk = 0; blk < nblk; blk++) {
    const int kv0 = blk * 32;
    f32x4_t s0 = {0.f, 0.f, 0.f, 0.f}, s1 = {0.f, 0.f, 0.f, 0.f};
    const unsigned short* k0p = kb + (long)(kv0 + r) * 128;
    const unsigned short* k1p = k0p + 16 * 128;
#pragma unroll
    for (int c = 0; c < 4; c++) {
      bf16x8_t kf0 = *(const bf16x8_t*)(k0p + c * 32);
      bf16x8_t kf1 = *(const bf16x8_t*)(k1p + c * 32);
      s0 = __builtin_amdgcn_mfma_f32_16x16x32_bf16(kf0, qf[c], s0, 0, 0, 0);
      s1 = __builtin_amdgcn_mfma_f32_16x16x32_bf16(kf1, qf[c], s1, 0, 0, 0);
    }
    // lane holds S[q0 + r][kv0 + 4g + j] (s0) and S[q0 + r][kv0 + 16 + 4g + j] (s1)
    const int q = q0 + r;
    if (kv0 + 31 > q0) {
#pragma unroll
      for (int j = 0; j < 4; j++) {
        if (kv0 + 4 * g + j > q) s0[j] = -1e30f;
        if (kv0 + 16 + 4 * g + j > q) s1[j] = -1e30f;
      }
    }
    float pm = fmaxf(fmaxf(fmaxf(s0[0], s0[1]), fmaxf(s0[2], s0[3])),
                     fmaxf(fmaxf(s1[0], s1[1]), fmaxf(s1[2], s1[3])));
    pm = fmaxf(pm, __shfl_xor(pm, 16));
    pm = fmaxf(pm, __shfl_xor(pm, 32));
    const float mnew = fmaxf(m, pm);
    const float alpha = __expf(m - mnew);
    float p[8];
#pragma unroll
    for (int j = 0; j < 4; j++) {
      p[j] = __expf(s0[j] - mnew);
      p[4 + j] = __expf(s1[j] - mnew);
    }
    float ps = p[0] + p[1] + p[2] + p[3] + p[4] + p[5] + p[6] + p[7];
    ps += __shfl_xor(ps, 16);
    ps += __shfl_xor(ps, 32);
    lsum = lsum * alpha + ps;
    m = mnew;
    float aj[4];
#pragma unroll
    for (int j = 0; j < 4; j++) aj[j] = __shfl(alpha, 4 * g + j);  // O rows are 4g+j
#pragma unroll
    for (int dt = 0; dt < 8; dt++) {
      o[dt][0] *= aj[0]; o[dt][1] *= aj[1]; o[dt][2] *= aj[2]; o[dt][3] *= aj[3];
    }
    // redistribute P through LDS: write [q=r][kv] (swizzled), read back A-frag row r, kv 8g..8g+7
    unsigned pk0 = (unsigned)f2bf(p[0]) | ((unsigned)f2bf(p[1]) << 16);
    unsigned pk1 = (unsigned)f2bf(p[2]) | ((unsigned)f2bf(p[3]) << 16);
    unsigned pk2 = (unsigned)f2bf(p[4]) | ((unsigned)f2bf(p[5]) << 16);
    unsigned pk3 = (unsigned)f2bf(p[6]) | ((unsigned)f2bf(p[7]) << 16);
    asm volatile("" ::: "memory");  // compiler barrier: defeat TBAA reordering vs prior read
    {
      unsigned short* rowp = pw + r * 32;
      *(unsigned*)(rowp + ((4 * g + 0) ^ swz)) = pk0;
      *(unsigned*)(rowp + ((4 * g + 2) ^ swz)) = pk1;
      *(unsigned*)(rowp + ((16 + 4 * g + 0) ^ swz)) = pk2;
      *(unsigned*)(rowp + ((16 + 4 * g + 2) ^ swz)) = pk3;
    }
    asm volatile("s_waitcnt lgkmcnt(0)" ::: "memory");
    const bf16x8_t pa = *(const bf16x8_t*)(pw + r * 32 + ((8 * g) ^ swz));
#pragma unroll
    for (int dt = 0; dt < 8; dt++) {
      const bf16x8_t vf = *(const bf16x8_t*)(vb + (long)(dt * 16 + r) * 2048 + kv0 + 8 * g);
      o[dt] = __builtin_amdgcn_mfma_f32_16x16x32_bf16(pa, vf, o[dt], 0, 0, 0);
    }
  }
  float rl[4];
#pragma unroll
  for (int j = 0; j < 4; j++) rl[j] = 1.0f / __shfl(lsum, 4 * g + j);
  // O[q0 + 4g + j][dt*16 + r] -> ao[(b,t)][h*128 + d]
  unsigned short* aop = ao + ((long)(b * 2048 + q0 + 4 * g)) * 2048 + h * 128 + r;
#pragma unroll
  for (int dt = 0; dt < 8; dt++)
#pragma unroll
    for (int j = 0; j < 4; j++)
      aop[(long)j * 2048 + dt * 16] = f2bf(o[dt][j] * rl[j]);
}

extern "C" void kernel_launch(void* const* d_in, const int* in_sizes, int n_in,
                              void* d_out, int out_size, void* d_ws, size_t ws_size,
                              hipStream_t stream) {
  const float* x    = (const float*)d_in[0];
  const float* sinp = (const float*)d_in[1];
  const float* cosp = (const float*)d_in[2];
  const float* Wqkv = (const float*)d_in[3];
  const float* Wo   = (const float*)d_in[4];
  float* out = (float*)d_out;
  char* ws = (char*)d_ws;

  const int B = 2, T = 2048, D = 2048, H = 16, HD = 128;
  const int M = B * T;        // 4096
  const int NQ = D + 2 * HD;  // 2304

  // workspace layout (bytes)
  unsigned short* xb    = (unsigned short*)(ws + 0);         // 16,777,216
  unsigned short* wqkvT = (unsigned short*)(ws + 16777216);  //  9,437,184
  unsigned short* woT   = (unsigned short*)(ws + 26214400);  //  8,388,608
  float*          qkv   = (float*)         (ws + 34603008);  // 37,748,736
  unsigned short* qr    = (unsigned short*)(ws + 72351744);  // 16,777,216
  unsigned short* kr    = (unsigned short*)(ws + 89128960);  //  1,048,576
  unsigned short* vT    = (unsigned short*)(ws + 90177536);  //  1,048,576
  unsigned short* ao    = xb;  // reuse xb after first GEMM (total ws use ~91.2 MB)

  dim3 tb(64, 4);
  // 1. x -> bf16
  cvt_bf16_kernel<<<(M * D) / 1024, 256, 0, stream>>>(x, xb);
  // 2. weight transposes (to [N][K] bf16)
  transpose_f32_bf16<<<dim3(NQ / 64, D / 64, 1), tb, 0, stream>>>(Wqkv, wqkvT, NQ, D, 0, 0);
  transpose_f32_bf16<<<dim3(D / 64, D / 64, 1), tb, 0, stream>>>(Wo, woT, D, D, 0, 0);
  // 3. qkv = x @ Wqkv   (fp32 out)
  gemm_bt<<<dim3(NQ / 128, M / 128), 256, 0, stream>>>(xb, wqkvT, qkv, M, NQ, D);
  // 4. rope + scale fold
  rope_kernel<<<M, 256, 0, stream>>>(qkv, sinp, cosp, qr, kr);
  // 5. v transpose: qkv[:, 2176:2304] -> vT (B,128,T)
  transpose_f32_bf16<<<dim3(HD / 64, T / 64, B), tb, 0, stream>>>(
      qkv + 2176, vT, NQ, T, (long)T * NQ, (long)HD * T);
  // 6. attention
  mqa_attn<<<dim3(T / 64, H, B), 256, 0, stream>>>(qr, kr, vT, ao);
  // 7. out = ao @ Wo
  gemm_bt<<<dim3(D / 128, M / 128), 256, 0, stream>>>(ao, woT, out, M, D, D);
}

// Round 2
// 454.105 us; speedup vs baseline: 1.3340x; 1.3340x over previous
//
#include <hip/hip_runtime.h>
#include <stdint.h>

typedef __bf16 bf16x8_t __attribute__((ext_vector_type(8)));
typedef float f32x4_t __attribute__((ext_vector_type(4)));

static __device__ __forceinline__ unsigned short f2bf(float f) {
  union { float f; unsigned u; } a;
  a.f = f;
  unsigned r = a.u + 0x7fffu + ((a.u >> 16) & 1u);
  return (unsigned short)(r >> 16);
}

static __device__ __forceinline__ unsigned pack2bf(float lo, float hi) {
  return (unsigned)f2bf(lo) | ((unsigned)f2bf(hi) << 16);
}

// ---------- 1. fp32 -> bf16 elementwise ----------
__global__ void cvt_bf16_kernel(const float* __restrict__ in, unsigned short* __restrict__ out) {
  long i = ((long)blockIdx.x * blockDim.x + threadIdx.x) * 4;
  float4 v = *(const float4*)(in + i);
  ushort4 o;
  o.x = f2bf(v.x);
  o.y = f2bf(v.y);
  o.z = f2bf(v.z);
  o.w = f2bf(v.w);
  *(ushort4*)(out + i) = o;
}

// ---------- 2. fp32 [R][C] (row stride ld) -> bf16 [C][R] (row stride dld) ----------
__global__ void transpose_f32_bf16(const float* __restrict__ src, unsigned short* __restrict__ dst,
                                   int ld, int dld, long sbs, long dbs) {
  __shared__ float tile[64][65];
  src += (long)blockIdx.z * sbs;
  dst += (long)blockIdx.z * dbs;
  const int c0 = blockIdx.x * 64, r0 = blockIdx.y * 64;
  const int tx = threadIdx.x, ty = threadIdx.y;
#pragma unroll
  for (int j = 0; j < 64; j += 4)
    tile[ty + j][tx] = src[(long)(r0 + ty + j) * ld + (c0 + tx)];
  __syncthreads();
#pragma unroll
  for (int j = 0; j < 64; j += 4)
    dst[(long)(c0 + ty + j) * dld + (r0 + tx)] = f2bf(tile[tx][ty + j]);
}

// ---------- 3. GEMM: C[M][N] = A[M][K] * Bt[N][K]^T  (bf16 in, fp32 out) ----------
__global__ __launch_bounds__(256) void gemm_bt(const unsigned short* __restrict__ A,
                                               const unsigned short* __restrict__ Bt,
                                               float* __restrict__ C,
                                               int M, int N, int K) {
  __shared__ unsigned short As[128 * 32];
  __shared__ unsigned short Bs[128 * 32];
  const int tid = threadIdx.x;
  const int wid = tid >> 6, lane = tid & 63;
  const int r16 = lane & 15, g = lane >> 4;
  const long bm = (long)blockIdx.y * 128;
  const long bn = (long)blockIdx.x * 128;
  const int wr = (wid >> 1) * 64, wc = (wid & 1) * 64;
  f32x4_t acc[4][4];
#pragma unroll
  for (int i = 0; i < 4; i++)
#pragma unroll
    for (int j = 0; j < 4; j++) acc[i][j] = (f32x4_t){0.f, 0.f, 0.f, 0.f};

  for (int kt = 0; kt < K; kt += 32) {
#pragma unroll
    for (int i = 0; i < 2; i++) {
      const int chunk = (i * 4 + wid) * 64 + lane;  // 512 chunks of 16B per tile
      const int row = chunk >> 2, col = (chunk & 3) * 8;
      __builtin_amdgcn_global_load_lds(
          (const __attribute__((address_space(1))) void*)(A + (bm + row) * K + kt + col),
          (__attribute__((address_space(3))) void*)(As + chunk * 8), 16, 0, 0);
      __builtin_amdgcn_global_load_lds(
          (const __attribute__((address_space(1))) void*)(Bt + (bn + row) * K + kt + col),
          (__attribute__((address_space(3))) void*)(Bs + chunk * 8), 16, 0, 0);
    }
    __syncthreads();
    bf16x8_t af[4], bfr[4];
#pragma unroll
    for (int mi = 0; mi < 4; mi++)
      af[mi] = *(const bf16x8_t*)(As + (wr + mi * 16 + r16) * 32 + g * 8);
#pragma unroll
    for (int ni = 0; ni < 4; ni++)
      bfr[ni] = *(const bf16x8_t*)(Bs + (wc + ni * 16 + r16) * 32 + g * 8);
#pragma unroll
    for (int mi = 0; mi < 4; mi++)
#pragma unroll
      for (int ni = 0; ni < 4; ni++)
        acc[mi][ni] = __builtin_amdgcn_mfma_f32_16x16x32_bf16(af[mi], bfr[ni], acc[mi][ni], 0, 0, 0);
    __syncthreads();
  }
#pragma unroll
  for (int mi = 0; mi < 4; mi++)
#pragma unroll
    for (int ni = 0; ni < 4; ni++) {
      const long rowb = bm + wr + mi * 16 + 4 * g;
      const long colb = bn + wc + ni * 16 + r16;
#pragma unroll
      for (int j = 0; j < 4; j++)
        C[(rowb + j) * N + colb] = acc[mi][ni][j];
    }
}

// ---------- 4. RoPE + scale fold + layout ----------
__global__ void rope_kernel(const float* __restrict__ qkv,
                            const float* __restrict__ sinp,
                            const float* __restrict__ cosp,
                            unsigned short* __restrict__ qr,
                            unsigned short* __restrict__ kr) {
  const int row = blockIdx.x;  // b*2048 + t
  const int b = row >> 11, t = row & 2047;
  const float* src = qkv + (long)row * 2304;
  const int tid = threadIdx.x;
  const int d = tid & 127;
  const int dp = (d + 64) & 127;
  const float c = cosp[t * 128 + d];
  const float s = sinp[t * 128 + d];
  const float sgn = (d < 64) ? -1.f : 1.f;
  for (int h = (tid >> 7); h < 16; h += 2) {
    const float x0 = src[h * 128 + d];
    const float xp = src[h * 128 + dp];
    qr[((long)((b * 16 + h) * 2048 + t)) * 128 + d] = f2bf((x0 * c + sgn * xp * s) * 0.0078125f);
  }
  if (tid < 128) {
    const float x0 = src[2048 + d];
    const float xp = src[2048 + dp];
    kr[((long)(b * 2048 + t)) * 128 + d] = f2bf(x0 * c + sgn * xp * s);
  }
}

// ---------- 5. causal MQA flash attention ----------
// Wave owns 16 q rows; KVBLK=64 per stage; swapped QK^T (lane owns q-row lane&15).
// Defer-max fast path (m=0, no cross-lane ops, no O rescale); row-sum reduce deferred
// to epilogue. P redistributed via per-wave XOR-swizzled LDS tile (2-way max).
__global__ __launch_bounds__(256, 4) void mqa_attn(const unsigned short* __restrict__ qr,
                                                   const unsigned short* __restrict__ kr,
                                                   const unsigned short* __restrict__ vT,
                                                   unsigned short* __restrict__ ao) {
  __shared__ unsigned short plds[4][16 * 64];  // per-wave 16x64 bf16 P tile (swizzled)
  const int idx = blockIdx.x;  // 1024 blocks
  const int tile = (idx + ((idx >> 8) << 3)) & 31;  // rotate tiles across CU residency sets
  const int h = (idx >> 5) & 15;
  const int b = idx >> 9;
  const int wid = threadIdx.x >> 6, lane = threadIdx.x & 63;
  const int r = lane & 15, g = lane >> 4;
  const int q0 = tile * 64 + wid * 16;
  const int rs = r & 7;  // 3-bit XOR slot swizzle
  char* pw = (char*)&plds[wid][0];

  bf16x8_t qf[4];
  const unsigned short* qp = qr + ((long)((b * 16 + h) * 2048 + q0 + r)) * 128 + g * 8;
#pragma unroll
  for (int c = 0; c < 4; c++) qf[c] = *(const bf16x8_t*)(qp + c * 32);

  f32x4_t o[8];
#pragma unroll
  for (int i = 0; i < 8; i++) o[i] = (f32x4_t){0.f, 0.f, 0.f, 0.f};
  float m = 0.f, lsum = 0.f;

  const unsigned short* kb = kr + (long)b * 2048 * 128 + g * 8;
  const unsigned short* vbr = vT + (long)b * 128 * 2048 + (long)r * 2048 + g * 8;
  const int nstg = q0 / 64 + 1;

  for (int stg = 0; stg < nstg; stg++) {
    const int kv0 = stg * 64;
    f32x4_t s[4];
#pragma unroll
    for (int t = 0; t < 4; t++) s[t] = (f32x4_t){0.f, 0.f, 0.f, 0.f};
    const unsigned short* kp = kb + (long)(kv0 + r) * 128;
    // QK^T in two t-halves to cap live K regs (~32 VGPR)
#pragma unroll
    for (int th = 0; th < 2; th++) {
      bf16x8_t kf[2][4];
#pragma unroll
      for (int t = 0; t < 2; t++)
#pragma unroll
        for (int c = 0; c < 4; c++)
          kf[t][c] = *(const bf16x8_t*)(kp + (th * 2 + t) * 16 * 128 + c * 32);
#pragma unroll
      for (int c = 0; c < 4; c++)
#pragma unroll
        for (int t = 0; t < 2; t++)
          s[th * 2 + t] = __builtin_amdgcn_mfma_f32_16x16x32_bf16(kf[t][c], qf[c], s[th * 2 + t], 0, 0, 0);
    }
    if (stg == nstg - 1) {  // causal mask (kv0 == (q0/64)*64 here)
#pragma unroll
      for (int t = 0; t < 4; t++) {
#pragma unroll
        for (int j = 0; j < 4; j++)
          if (t * 16 + 4 * g + j > wid * 16 + r) s[t][j] = -1e30f;
      }
    }
    // local max only; cross-lane max avoided unless threshold exceeded
    float lm = s[0][0];
#pragma unroll
    for (int t = 0; t < 4; t++)
#pragma unroll
      for (int j = 0; j < 4; j++) lm = fmaxf(lm, s[t][j]);
    if (!__all(lm <= m + 8.f)) {  // rare rescale path
      float pm = lm;
      pm = fmaxf(pm, __shfl_xor(pm, 16));
      pm = fmaxf(pm, __shfl_xor(pm, 32));
      const float mnew = fmaxf(m, pm);
      const float alpha = __expf(m - mnew);
      lsum *= alpha;
      float aj[4];
#pragma unroll
      for (int j = 0; j < 4; j++) aj[j] = __shfl(alpha, 4 * g + j);
#pragma unroll
      for (int dt = 0; dt < 8; dt++) {
        o[dt][0] *= aj[0]; o[dt][1] *= aj[1]; o[dt][2] *= aj[2]; o[dt][3] *= aj[3];
      }
      m = mnew;
    }
    float p[16];
#pragma unroll
    for (int t = 0; t < 4; t++)
#pragma unroll
      for (int j = 0; j < 4; j++) p[4 * t + j] = __expf(s[t][j] - m);
    float ls = 0.f;
#pragma unroll
    for (int i = 0; i < 16; i++) ls += p[i];
    lsum += ls;  // cross-lane sum deferred to epilogue

    // issue V half0 loads before the LDS round-trip so latency hides under it
    bf16x8_t vf0[8];
#pragma unroll
    for (int dt = 0; dt < 8; dt++) vf0[dt] = *(const bf16x8_t*)(vbr + (long)dt * 16 * 2048 + kv0);

    asm volatile("" ::: "memory");
    // write P row r, kv chunk 16t+4g..+3 : 8B store at swizzled slot
#pragma unroll
    for (int t = 0; t < 4; t++) {
      uint2 w = {pack2bf(p[4 * t], p[4 * t + 1]), pack2bf(p[4 * t + 2], p[4 * t + 3])};
      *(uint2*)(pw + r * 128 + (((2 * t + (g >> 1)) ^ rs) << 4) + ((g & 1) << 3)) = w;
    }
    asm volatile("s_waitcnt lgkmcnt(0)" ::: "memory");
    const bf16x8_t pa0 = *(const bf16x8_t*)(pw + r * 128 + ((g ^ rs) << 4));
    const bf16x8_t pa1 = *(const bf16x8_t*)(pw + r * 128 + (((4 + g) ^ rs) << 4));
#pragma unroll
    for (int dt = 0; dt < 8; dt++)
      o[dt] = __builtin_amdgcn_mfma_f32_16x16x32_bf16(pa0, vf0[dt], o[dt], 0, 0, 0);
#pragma unroll
    for (int dt = 0; dt < 8; dt++) {
      const bf16x8_t vf1 = *(const bf16x8_t*)(vbr + (long)dt * 16 * 2048 + kv0 + 32);
      o[dt] = __builtin_amdgcn_mfma_f32_16x16x32_bf16(pa1, vf1, o[dt], 0, 0, 0);
    }
  }
  lsum += __shfl_xor(lsum, 16);
  lsum += __shfl_xor(lsum, 32);
  float rl[4];
#pragma unroll
  for (int j = 0; j < 4; j++) rl[j] = 1.0f / __shfl(lsum, 4 * g + j);
  unsigned short* aop = ao + ((long)(b * 2048 + q0 + 4 * g)) * 2048 + h * 128 + r;
#pragma unroll
  for (int dt = 0; dt < 8; dt++)
#pragma unroll
    for (int j = 0; j < 4; j++)
      aop[(long)j * 2048 + dt * 16] = f2bf(o[dt][j] * rl[j]);
}

extern "C" void kernel_launch(void* const* d_in, const int* in_sizes, int n_in,
                              void* d_out, int out_size, void* d_ws, size_t ws_size,
                              hipStream_t stream) {
  const float* x    = (const float*)d_in[0];
  const float* sinp = (const float*)d_in[1];
  const float* cosp = (const float*)d_in[2];
  const float* Wqkv = (const float*)d_in[3];
  const float* Wo   = (const float*)d_in[4];
  float* out = (float*)d_out;
  char* ws = (char*)d_ws;

  const int B = 2, T = 2048, D = 2048, H = 16, HD = 128;
  const int M = B * T;        // 4096
  const int NQ = D + 2 * HD;  // 2304

  unsigned short* xb    = (unsigned short*)(ws + 0);         // 16,777,216
  unsigned short* wqkvT = (unsigned short*)(ws + 16777216);  //  9,437,184
  unsigned short* woT   = (unsigned short*)(ws + 26214400);  //  8,388,608
  float*          qkv   = (float*)         (ws + 34603008);  // 37,748,736
  unsigned short* qr    = (unsigned short*)(ws + 72351744);  // 16,777,216
  unsigned short* kr    = (unsigned short*)(ws + 89128960);  //  1,048,576
  unsigned short* vT    = (unsigned short*)(ws + 90177536);  //  1,048,576
  unsigned short* ao    = xb;  // reuse xb after first GEMM

  dim3 tb(64, 4);
  cvt_bf16_kernel<<<(M * D) / 1024, 256, 0, stream>>>(x, xb);
  transpose_f32_bf16<<<dim3(NQ / 64, D / 64, 1), tb, 0, stream>>>(Wqkv, wqkvT, NQ, D, 0, 0);
  transpose_f32_bf16<<<dim3(D / 64, D / 64, 1), tb, 0, stream>>>(Wo, woT, D, D, 0, 0);
  gemm_bt<<<dim3(NQ / 128, M / 128), 256, 0, stream>>>(xb, wqkvT, qkv, M, NQ, D);
  rope_kernel<<<M, 256, 0, stream>>>(qkv, sinp, cosp, qr, kr);
  transpose_f32_bf16<<<dim3(HD / 64, T / 64, B), tb, 0, stream>>>(
      qkv + 2176, vT, NQ, T, (long)T * NQ, (long)HD * T);
  mqa_attn<<<dim3(T / 64 * H * B), 256, 0, stream>>>(qr, kr, vT, ao);
  gemm_bt<<<dim3(D / 128, M / 128), 256, 0, stream>>>(ao, woT, out, M, D, D);
}

// Round 3
// 406.848 us; speedup vs baseline: 1.4890x; 1.1162x over previous
//
#include <hip/hip_runtime.h>
#include <stdint.h>

typedef __bf16 bf16x8_t __attribute__((ext_vector_type(8)));
typedef float f32x4_t __attribute__((ext_vector_type(4)));

static __device__ __forceinline__ unsigned short f2bf(float f) {
  union { float f; unsigned u; } a;
  a.f = f;
  unsigned r = a.u + 0x7fffu + ((a.u >> 16) & 1u);
  return (unsigned short)(r >> 16);
}

static __device__ __forceinline__ unsigned pack2bf(float lo, float hi) {
  return (unsigned)f2bf(lo) | ((unsigned)f2bf(hi) << 16);
}

// ---------- 1. fp32 -> bf16 elementwise ----------
__global__ void cvt_bf16_kernel(const float* __restrict__ in, unsigned short* __restrict__ out) {
  long i = ((long)blockIdx.x * blockDim.x + threadIdx.x) * 4;
  float4 v = *(const float4*)(in + i);
  ushort4 o;
  o.x = f2bf(v.x);
  o.y = f2bf(v.y);
  o.z = f2bf(v.z);
  o.w = f2bf(v.w);
  *(ushort4*)(out + i) = o;
}

// ---------- 2. fp32 [R][C] (row stride ld) -> bf16 [C][R] (row stride dld) ----------
__global__ void transpose_f32_bf16(const float* __restrict__ src, unsigned short* __restrict__ dst,
                                   int ld, int dld, long sbs, long dbs) {
  __shared__ float tile[64][65];
  src += (long)blockIdx.z * sbs;
  dst += (long)blockIdx.z * dbs;
  const int c0 = blockIdx.x * 64, r0 = blockIdx.y * 64;
  const int tx = threadIdx.x, ty = threadIdx.y;
#pragma unroll
  for (int j = 0; j < 64; j += 4)
    tile[ty + j][tx] = src[(long)(r0 + ty + j) * ld + (c0 + tx)];
  __syncthreads();
#pragma unroll
  for (int j = 0; j < 64; j += 4)
    dst[(long)(c0 + ty + j) * dld + (r0 + tx)] = f2bf(tile[tx][ty + j]);
}

// ---------- 3. GEMM: C[M][N] = A[M][K] * Bt[N][K]^T  (bf16 in, fp32 out) ----------
__global__ __launch_bounds__(256) void gemm_bt(const unsigned short* __restrict__ A,
                                               const unsigned short* __restrict__ Bt,
                                               float* __restrict__ C,
                                               int M, int N, int K) {
  __shared__ unsigned short As[128 * 32];
  __shared__ unsigned short Bs[128 * 32];
  const int tid = threadIdx.x;
  const int wid = tid >> 6, lane = tid & 63;
  const int r16 = lane & 15, g = lane >> 4;
  const long bm = (long)blockIdx.y * 128;
  const long bn = (long)blockIdx.x * 128;
  const int wr = (wid >> 1) * 64, wc = (wid & 1) * 64;
  f32x4_t acc[4][4];
#pragma unroll
  for (int i = 0; i < 4; i++)
#pragma unroll
    for (int j = 0; j < 4; j++) acc[i][j] = (f32x4_t){0.f, 0.f, 0.f, 0.f};

  for (int kt = 0; kt < K; kt += 32) {
#pragma unroll
    for (int i = 0; i < 2; i++) {
      const int chunk = (i * 4 + wid) * 64 + lane;  // 512 chunks of 16B per tile
      const int row = chunk >> 2, col = (chunk & 3) * 8;
      __builtin_amdgcn_global_load_lds(
          (const __attribute__((address_space(1))) void*)(A + (bm + row) * K + kt + col),
          (__attribute__((address_space(3))) void*)(As + chunk * 8), 16, 0, 0);
      __builtin_amdgcn_global_load_lds(
          (const __attribute__((address_space(1))) void*)(Bt + (bn + row) * K + kt + col),
          (__attribute__((address_space(3))) void*)(Bs + chunk * 8), 16, 0, 0);
    }
    __syncthreads();
    bf16x8_t af[4], bfr[4];
#pragma unroll
    for (int mi = 0; mi < 4; mi++)
      af[mi] = *(const bf16x8_t*)(As + (wr + mi * 16 + r16) * 32 + g * 8);
#pragma unroll
    for (int ni = 0; ni < 4; ni++)
      bfr[ni] = *(const bf16x8_t*)(Bs + (wc + ni * 16 + r16) * 32 + g * 8);
#pragma unroll
    for (int mi = 0; mi < 4; mi++)
#pragma unroll
      for (int ni = 0; ni < 4; ni++)
        acc[mi][ni] = __builtin_amdgcn_mfma_f32_16x16x32_bf16(af[mi], bfr[ni], acc[mi][ni], 0, 0, 0);
    __syncthreads();
  }
#pragma unroll
  for (int mi = 0; mi < 4; mi++)
#pragma unroll
    for (int ni = 0; ni < 4; ni++) {
      const long rowb = bm + wr + mi * 16 + 4 * g;
      const long colb = bn + wc + ni * 16 + r16;
#pragma unroll
      for (int j = 0; j < 4; j++)
        C[(rowb + j) * N + colb] = acc[mi][ni][j];
    }
}

// ---------- 4. RoPE + scale fold + layout ----------
__global__ void rope_kernel(const float* __restrict__ qkv,
                            const float* __restrict__ sinp,
                            const float* __restrict__ cosp,
                            unsigned short* __restrict__ qr,
                            unsigned short* __restrict__ kr) {
  const int row = blockIdx.x;  // b*2048 + t
  const int b = row >> 11, t = row & 2047;
  const float* src = qkv + (long)row * 2304;
  const int tid = threadIdx.x;
  const int d = tid & 127;
  const int dp = (d + 64) & 127;
  const float c = cosp[t * 128 + d];
  const float s = sinp[t * 128 + d];
  const float sgn = (d < 64) ? -1.f : 1.f;
  for (int h = (tid >> 7); h < 16; h += 2) {
    const float x0 = src[h * 128 + d];
    const float xp = src[h * 128 + dp];
    qr[((long)((b * 16 + h) * 2048 + t)) * 128 + d] = f2bf((x0 * c + sgn * xp * s) * 0.0078125f);
  }
  if (tid < 128) {
    const float x0 = src[2048 + d];
    const float xp = src[2048 + dp];
    kr[((long)(b * 2048 + t)) * 128 + d] = f2bf(x0 * c + sgn * xp * s);
  }
}

// ---------- 5. causal MQA flash attention ----------
// Each wave processes TWO complementary 16-row q strips (strip s and 127-s):
// exactly 33 stages per wave -> perfect balance. KVBLK=64, swapped QK^T,
// defer-max fast path, K prefetch pipelined under PV.
// amdgpu_waves_per_eu(3,3): VGPR budget 168 so the ~135-reg working set
// does NOT spill (round-2 allocator pinned 64 VGPRs and spilled -> 11k cyc/stage).
__global__ __launch_bounds__(256) __attribute__((amdgpu_waves_per_eu(3, 3)))
void mqa_attn(const unsigned short* __restrict__ qr,
              const unsigned short* __restrict__ kr,
              const unsigned short* __restrict__ vT,
              unsigned short* __restrict__ ao) {
  __shared__ unsigned short plds[4][16 * 64];  // per-wave 16x64 bf16 P tile (swizzled)
  const int idx = blockIdx.x;  // 512 blocks: b(1) x h(4) x j(4)
  const int j16 = idx & 15, h = (idx >> 4) & 15, b = idx >> 8;
  const int wid = threadIdx.x >> 6, lane = threadIdx.x & 63;
  const int r = lane & 15, g = lane >> 4;
  const int rs = r & 7;  // 3-bit XOR slot swizzle
  char* pw = (char*)&plds[wid][0];

  const unsigned short* kb = kr + (long)b * 2048 * 128 + g * 8;
  const unsigned short* vbr = vT + (long)b * 128 * 2048 + (long)r * 2048 + g * 8;
  const unsigned short* qh = qr + ((long)(b * 16 + h) * 2048) * 128;

  for (int half = 0; half < 2; half++) {
    const int strip = (half == 0) ? (j16 * 4 + wid) : (127 - j16 * 4 - wid);
    const int q0 = strip * 16;
    const int nstg = (strip >> 2) + 1;
    const int qrow = (strip & 3) * 16 + r;  // q row offset within last stage's kv block

    bf16x8_t qf[4];
    const unsigned short* qp = qh + (long)(q0 + r) * 128 + g * 8;
#pragma unroll
    for (int c = 0; c < 4; c++) qf[c] = *(const bf16x8_t*)(qp + c * 32);

    f32x4_t o[8];
#pragma unroll
    for (int i = 0; i < 8; i++) o[i] = (f32x4_t){0.f, 0.f, 0.f, 0.f};
    float m = 0.f, lsum = 0.f;

    // prologue: preload K groups 0,1 of stage 0
    bf16x8_t kfp[2][4];
#pragma unroll
    for (int t = 0; t < 2; t++)
#pragma unroll
      for (int c = 0; c < 4; c++)
        kfp[t][c] = *(const bf16x8_t*)(kb + (long)(t * 16 + r) * 128 + c * 32);

    for (int stg = 0; stg < nstg; stg++) {
      const int kv0 = stg * 64;
      f32x4_t s[4];
#pragma unroll
      for (int t = 0; t < 4; t++) s[t] = (f32x4_t){0.f, 0.f, 0.f, 0.f};
      // groups 0,1 from prefetched regs
#pragma unroll
      for (int c = 0; c < 4; c++)
#pragma unroll
        for (int t = 0; t < 2; t++)
          s[t] = __builtin_amdgcn_mfma_f32_16x16x32_bf16(kfp[t][c], qf[c], s[t], 0, 0, 0);
      // groups 2,3 fresh
      {
        bf16x8_t kf2[2][4];
#pragma unroll
        for (int t = 0; t < 2; t++)
#pragma unroll
          for (int c = 0; c < 4; c++)
            kf2[t][c] = *(const bf16x8_t*)(kb + (long)(kv0 + (2 + t) * 16 + r) * 128 + c * 32);
#pragma unroll
        for (int c = 0; c < 4; c++)
#pragma unroll
          for (int t = 0; t < 2; t++)
            s[2 + t] = __builtin_amdgcn_mfma_f32_16x16x32_bf16(kf2[t][c], qf[c], s[2 + t], 0, 0, 0);
      }
      if (stg == nstg - 1) {  // causal mask
#pragma unroll
        for (int t = 0; t < 4; t++)
#pragma unroll
          for (int jj = 0; jj < 4; jj++)
            if (t * 16 + 4 * g + jj > qrow) s[t][jj] = -1e30f;
      }
      float lm = s[0][0];
#pragma unroll
      for (int t = 0; t < 4; t++)
#pragma unroll
        for (int jj = 0; jj < 4; jj++) lm = fmaxf(lm, s[t][jj]);
      if (!__all(lm <= m + 8.f)) {  // rare rescale path
        float pm = lm;
        pm = fmaxf(pm, __shfl_xor(pm, 16));
        pm = fmaxf(pm, __shfl_xor(pm, 32));
        const float mnew = fmaxf(m, pm);
        const float alpha = __expf(m - mnew);
        lsum *= alpha;
        float aj[4];
#pragma unroll
        for (int jj = 0; jj < 4; jj++) aj[jj] = __shfl(alpha, 4 * g + jj);
#pragma unroll
        for (int dt = 0; dt < 8; dt++) {
          o[dt][0] *= aj[0]; o[dt][1] *= aj[1]; o[dt][2] *= aj[2]; o[dt][3] *= aj[3];
        }
        m = mnew;
      }
      float p[16];
#pragma unroll
      for (int t = 0; t < 4; t++)
#pragma unroll
        for (int jj = 0; jj < 4; jj++) p[4 * t + jj] = __expf(s[t][jj] - m);
      float ls = 0.f;
#pragma unroll
      for (int i = 0; i < 16; i++) ls += p[i];
      lsum += ls;  // cross-lane sum deferred to epilogue

      // issue V half0 loads before the LDS round-trip so latency hides under it
      bf16x8_t vf0[8];
#pragma unroll
      for (int dt = 0; dt < 8; dt++) vf0[dt] = *(const bf16x8_t*)(vbr + (long)dt * 16 * 2048 + kv0);

      asm volatile("" ::: "memory");
#pragma unroll
      for (int t = 0; t < 4; t++) {
        uint2 w = {pack2bf(p[4 * t], p[4 * t + 1]), pack2bf(p[4 * t + 2], p[4 * t + 3])};
        *(uint2*)(pw + r * 128 + (((2 * t + (g >> 1)) ^ rs) << 4) + ((g & 1) << 3)) = w;
      }
      asm volatile("s_waitcnt lgkmcnt(0)" ::: "memory");
      const bf16x8_t pa0 = *(const bf16x8_t*)(pw + r * 128 + ((g ^ rs) << 4));
      const bf16x8_t pa1 = *(const bf16x8_t*)(pw + r * 128 + (((4 + g) ^ rs) << 4));
      // prefetch next stage's K groups 0,1 (kfp regs are free here; hides K latency)
      if (stg + 1 < nstg) {
#pragma unroll
        for (int t = 0; t < 2; t++)
#pragma unroll
          for (int c = 0; c < 4; c++)
            kfp[t][c] = *(const bf16x8_t*)(kb + (long)(kv0 + 64 + t * 16 + r) * 128 + c * 32);
      }
#pragma unroll
      for (int dt = 0; dt < 8; dt++)
        o[dt] = __builtin_amdgcn_mfma_f32_16x16x32_bf16(pa0, vf0[dt], o[dt], 0, 0, 0);
#pragma unroll
      for (int dt = 0; dt < 8; dt++) {
        const bf16x8_t vf1 = *(const bf16x8_t*)(vbr + (long)dt * 16 * 2048 + kv0 + 32);
        o[dt] = __builtin_amdgcn_mfma_f32_16x16x32_bf16(pa1, vf1, o[dt], 0, 0, 0);
      }
    }
    lsum += __shfl_xor(lsum, 16);
    lsum += __shfl_xor(lsum, 32);
    float rl[4];
#pragma unroll
    for (int jj = 0; jj < 4; jj++) rl[jj] = 1.0f / __shfl(lsum, 4 * g + jj);
    unsigned short* aop = ao + ((long)(b * 2048 + q0 + 4 * g)) * 2048 + h * 128 + r;
#pragma unroll
    for (int dt = 0; dt < 8; dt++)
#pragma unroll
      for (int jj = 0; jj < 4; jj++)
        aop[(long)jj * 2048 + dt * 16] = f2bf(o[dt][jj] * rl[jj]);
  }
}

extern "C" void kernel_launch(void* const* d_in, const int* in_sizes, int n_in,
                              void* d_out, int out_size, void* d_ws, size_t ws_size,
                              hipStream_t stream) {
  const float* x    = (const float*)d_in[0];
  const float* sinp = (const float*)d_in[1];
  const float* cosp = (const float*)d_in[2];
  const float* Wqkv = (const float*)d_in[3];
  const float* Wo   = (const float*)d_in[4];
  float* out = (float*)d_out;
  char* ws = (char*)d_ws;

  const int B = 2, T = 2048, D = 2048, H = 16, HD = 128;
  const int M = B * T;        // 4096
  const int NQ = D + 2 * HD;  // 2304

  unsigned short* xb    = (unsigned short*)(ws + 0);         // 16,777,216
  unsigned short* wqkvT = (unsigned short*)(ws + 16777216);  //  9,437,184
  unsigned short* woT   = (unsigned short*)(ws + 26214400);  //  8,388,608
  float*          qkv   = (float*)         (ws + 34603008);  // 37,748,736
  unsigned short* qr    = (unsigned short*)(ws + 72351744);  // 16,777,216
  unsigned short* kr    = (unsigned short*)(ws + 89128960);  //  1,048,576
  unsigned short* vT    = (unsigned short*)(ws + 90177536);  //  1,048,576
  unsigned short* ao    = xb;  // reuse xb after first GEMM

  dim3 tb(64, 4);
  cvt_bf16_kernel<<<(M * D) / 1024, 256, 0, stream>>>(x, xb);
  transpose_f32_bf16<<<dim3(NQ / 64, D / 64, 1), tb, 0, stream>>>(Wqkv, wqkvT, NQ, D, 0, 0);
  transpose_f32_bf16<<<dim3(D / 64, D / 64, 1), tb, 0, stream>>>(Wo, woT, D, D, 0, 0);
  gemm_bt<<<dim3(NQ / 128, M / 128), 256, 0, stream>>>(xb, wqkvT, qkv, M, NQ, D);
  rope_kernel<<<M, 256, 0, stream>>>(qkv, sinp, cosp, qr, kr);
  transpose_f32_bf16<<<dim3(HD / 64, T / 64, B), tb, 0, stream>>>(
      qkv + 2176, vT, NQ, T, (long)T * NQ, (long)HD * T);
  mqa_attn<<<dim3(512), 256, 0, stream>>>(qr, kr, vT, ao);
  gemm_bt<<<dim3(D / 128, M / 128), 256, 0, stream>>>(ao, woT, out, M, D, D);
}

// Round 4
// 304.350 us; speedup vs baseline: 1.9905x; 1.3368x over previous
//
#include <hip/hip_runtime.h>
#include <stdint.h>

typedef __bf16 bf16x8_t __attribute__((ext_vector_type(8)));
typedef float f32x4_t __attribute__((ext_vector_type(4)));

#define AS1 __attribute__((address_space(1)))
#define AS3 __attribute__((address_space(3)))

static __device__ __forceinline__ unsigned short f2bf(float f) {
  union { float f; unsigned u; } a;
  a.f = f;
  unsigned r = a.u + 0x7fffu + ((a.u >> 16) & 1u);
  return (unsigned short)(r >> 16);
}

static __device__ __forceinline__ unsigned pack2bf(float lo, float hi) {
  return (unsigned)f2bf(lo) | ((unsigned)f2bf(hi) << 16);
}

// ---------- 1. fp32 -> bf16 elementwise ----------
__global__ void cvt_bf16_kernel(const float* __restrict__ in, unsigned short* __restrict__ out) {
  long i = ((long)blockIdx.x * blockDim.x + threadIdx.x) * 4;
  float4 v = *(const float4*)(in + i);
  ushort4 o;
  o.x = f2bf(v.x);
  o.y = f2bf(v.y);
  o.z = f2bf(v.z);
  o.w = f2bf(v.w);
  *(ushort4*)(out + i) = o;
}

// ---------- 2. fp32 [R][C] (row stride ld) -> bf16 [C][R] (row stride dld) ----------
__global__ void transpose_f32_bf16(const float* __restrict__ src, unsigned short* __restrict__ dst,
                                   int ld, int dld, long sbs, long dbs) {
  __shared__ float tile[64][65];
  src += (long)blockIdx.z * sbs;
  dst += (long)blockIdx.z * dbs;
  const int c0 = blockIdx.x * 64, r0 = blockIdx.y * 64;
  const int tx = threadIdx.x, ty = threadIdx.y;
#pragma unroll
  for (int j = 0; j < 64; j += 4)
    tile[ty + j][tx] = src[(long)(r0 + ty + j) * ld + (c0 + tx)];
  __syncthreads();
#pragma unroll
  for (int j = 0; j < 64; j += 4)
    dst[(long)(c0 + ty + j) * dld + (r0 + tx)] = f2bf(tile[tx][ty + j]);
}

// ---------- 3. GEMM: C[M][N] = A[M][K] * Bt[N][K]^T  (bf16 in, fp32 out) ----------
__global__ __launch_bounds__(256) void gemm_bt(const unsigned short* __restrict__ A,
                                               const unsigned short* __restrict__ Bt,
                                               float* __restrict__ C,
                                               int M, int N, int K) {
  __shared__ unsigned short As[128 * 32];
  __shared__ unsigned short Bs[128 * 32];
  const int tid = threadIdx.x;
  const int wid = tid >> 6, lane = tid & 63;
  const int r16 = lane & 15, g = lane >> 4;
  const long bm = (long)blockIdx.y * 128;
  const long bn = (long)blockIdx.x * 128;
  const int wr = (wid >> 1) * 64, wc = (wid & 1) * 64;
  f32x4_t acc[4][4];
#pragma unroll
  for (int i = 0; i < 4; i++)
#pragma unroll
    for (int j = 0; j < 4; j++) acc[i][j] = (f32x4_t){0.f, 0.f, 0.f, 0.f};

  for (int kt = 0; kt < K; kt += 32) {
#pragma unroll
    for (int i = 0; i < 2; i++) {
      const int chunk = (i * 4 + wid) * 64 + lane;
      const int row = chunk >> 2, col = (chunk & 3) * 8;
      __builtin_amdgcn_global_load_lds(
          (const AS1 void*)(A + (bm + row) * K + kt + col),
          (AS3 void*)(As + chunk * 8), 16, 0, 0);
      __builtin_amdgcn_global_load_lds(
          (const AS1 void*)(Bt + (bn + row) * K + kt + col),
          (AS3 void*)(Bs + chunk * 8), 16, 0, 0);
    }
    __syncthreads();
    bf16x8_t af[4], bfr[4];
#pragma unroll
    for (int mi = 0; mi < 4; mi++)
      af[mi] = *(const bf16x8_t*)(As + (wr + mi * 16 + r16) * 32 + g * 8);
#pragma unroll
    for (int ni = 0; ni < 4; ni++)
      bfr[ni] = *(const bf16x8_t*)(Bs + (wc + ni * 16 + r16) * 32 + g * 8);
#pragma unroll
    for (int mi = 0; mi < 4; mi++)
#pragma unroll
      for (int ni = 0; ni < 4; ni++)
        acc[mi][ni] = __builtin_amdgcn_mfma_f32_16x16x32_bf16(af[mi], bfr[ni], acc[mi][ni], 0, 0, 0);
    __syncthreads();
  }
#pragma unroll
  for (int mi = 0; mi < 4; mi++)
#pragma unroll
    for (int ni = 0; ni < 4; ni++) {
      const long rowb = bm + wr + mi * 16 + 4 * g;
      const long colb = bn + wc + ni * 16 + r16;
#pragma unroll
      for (int j = 0; j < 4; j++)
        C[(rowb + j) * N + colb] = acc[mi][ni][j];
    }
}

// ---------- 4. RoPE + scale fold + layout ----------
__global__ void rope_kernel(const float* __restrict__ qkv,
                            const float* __restrict__ sinp,
                            const float* __restrict__ cosp,
                            unsigned short* __restrict__ qr,
                            unsigned short* __restrict__ kr) {
  const int row = blockIdx.x;  // b*2048 + t
  const int b = row >> 11, t = row & 2047;
  const float* src = qkv + (long)row * 2304;
  const int tid = threadIdx.x;
  const int d = tid & 127;
  const int dp = (d + 64) & 127;
  const float c = cosp[t * 128 + d];
  const float s = sinp[t * 128 + d];
  const float sgn = (d < 64) ? -1.f : 1.f;
  for (int h = (tid >> 7); h < 16; h += 2) {
    const float x0 = src[h * 128 + d];
    const float xp = src[h * 128 + dp];
    qr[((long)((b * 16 + h) * 2048 + t)) * 128 + d] = f2bf((x0 * c + sgn * xp * s) * 0.0078125f);
  }
  if (tid < 128) {
    const float x0 = src[2048 + d];
    const float xp = src[2048 + dp];
    kr[((long)(b * 2048 + t)) * 128 + d] = f2bf(x0 * c + sgn * xp * s);
  }
}

// ---------- 5. causal MQA flash attention (v4) ----------
// Block = 4 waves x 16 q-rows = one 64-row q-tile; processes tile j then tile 31-j
// (uniform 33 stages). K tile [64][128] staged to LDS via global_load_lds (async,
// double-buffered, XOR-swizzled via pre-swizzled global source). V direct-to-reg,
// bulk-issued early each stage. Swapped QK^T, defer-max (m=0), deferred row-sum.
// __launch_bounds__(256,2): 256-VGPR budget so vf[16]/o[8]/qf stay resident.
__global__ __launch_bounds__(256, 2)
void mqa_attn(const unsigned short* __restrict__ qr,
              const unsigned short* __restrict__ kr,
              const unsigned short* __restrict__ vT,
              unsigned short* __restrict__ ao) {
  __shared__ unsigned short Kb[2][64 * 128];   // 2 x 16KB K tiles
  __shared__ unsigned short plds[4][16 * 64];  // per-wave P tile (2KB each)
  const int idx = blockIdx.x;  // 512 blocks: b(1) x h(4) x pair(4)
  const int pj = idx & 15, h = (idx >> 4) & 15, b = idx >> 8;
  const int tid = threadIdx.x;
  const int wid = tid >> 6, lane = tid & 63;
  const int r = lane & 15, g = lane >> 4;
  const int rs = r & 7;
  char* pw = (char*)&plds[wid][0];

  const unsigned short* kbase = kr + (long)b * 2048 * 128;
  const unsigned short* vbr = vT + (long)b * 128 * 2048 + (long)r * 2048 + g * 8;
  const unsigned short* qh = qr + (long)(b * 16 + h) * 2048 * 128;

  // staging geometry: chunk c = i*256 + tid; row = c>>4, col = c&15 (16B units)
  const int scol = (tid & 15) ^ ((tid >> 4) & 7);  // pre-swizzled source col

  f32x4_t o[8];
#pragma unroll
  for (int i = 0; i < 8; i++) o[i] = (f32x4_t){0.f, 0.f, 0.f, 0.f};
  float m = 0.f, lsum = 0.f;

  int tile = pj;
  bf16x8_t qf[4];
  {
    const unsigned short* qp = qh + (long)(tile * 64 + wid * 16 + r) * 128 + g * 8;
#pragma unroll
    for (int c = 0; c < 4; c++) qf[c] = *(const bf16x8_t*)(qp + c * 32);
  }

  // prologue: stage kv-block 0 into buf 0
#pragma unroll
  for (int i = 0; i < 4; i++) {
    const int row = i * 16 + (tid >> 4);
    __builtin_amdgcn_global_load_lds(
        (const AS1 void*)(kbase + (long)row * 128 + scol * 8),
        (AS3 void*)(&Kb[0][(i * 256 + tid) * 8]), 16, 0, 0);
  }
  asm volatile("s_waitcnt vmcnt(0)" ::: "memory");
  __builtin_amdgcn_s_barrier();

  const int switch_s = pj + 1;
  for (int s = 0; s <= 32; s++) {
    const int cur = s & 1;
    // issue async staging of next kv tile into the other buffer
    if (s < 32) {
      const int kvn = (s + 1 <= pj) ? 64 * (s + 1) : 64 * (s - pj);
#pragma unroll
      for (int i = 0; i < 4; i++) {
        const int row = i * 16 + (tid >> 4);
        __builtin_amdgcn_global_load_lds(
            (const AS1 void*)(kbase + (long)(kvn + row) * 128 + scol * 8),
            (AS3 void*)(&Kb[cur ^ 1][(i * 256 + tid) * 8]), 16, 0, 0);
      }
    }
    // tile switch: flush tile A, reset state, load tile B's Q
    if (s == switch_s) {
      float lt = lsum;
      lt += __shfl_xor(lt, 16);
      lt += __shfl_xor(lt, 32);
      float rl[4];
#pragma unroll
      for (int jj = 0; jj < 4; jj++) rl[jj] = 1.0f / __shfl(lt, 4 * g + jj);
      unsigned short* aop = ao + ((long)(b * 2048 + tile * 64 + wid * 16 + 4 * g)) * 2048 + h * 128 + r;
#pragma unroll
      for (int dt = 0; dt < 8; dt++)
#pragma unroll
        for (int jj = 0; jj < 4; jj++)
          aop[(long)jj * 2048 + dt * 16] = f2bf(o[dt][jj] * rl[jj]);
      tile = 31 - pj;
      const unsigned short* qp = qh + (long)(tile * 64 + wid * 16 + r) * 128 + g * 8;
#pragma unroll
      for (int c = 0; c < 4; c++) qf[c] = *(const bf16x8_t*)(qp + c * 32);
#pragma unroll
      for (int i = 0; i < 8; i++) o[i] = (f32x4_t){0.f, 0.f, 0.f, 0.f};
      m = 0.f;
      lsum = 0.f;
    }
    const int kv0 = (s <= pj) ? 64 * s : 64 * (s - 1 - pj);

    // V loads: bulk-issue early; in flight during QK + softmax
    bf16x8_t vf[16];
#pragma unroll
    for (int dt = 0; dt < 8; dt++) {
      vf[dt] = *(const bf16x8_t*)(vbr + (long)dt * 16 * 2048 + kv0);
      vf[8 + dt] = *(const bf16x8_t*)(vbr + (long)dt * 16 * 2048 + kv0 + 32);
    }

    // QK^T from LDS K tile (swizzled reads: chunk (4c+g)^rs, row 16t+r)
    f32x4_t sc[4];
#pragma unroll
    for (int t = 0; t < 4; t++) sc[t] = (f32x4_t){0.f, 0.f, 0.f, 0.f};
    const unsigned short* Kcur = &Kb[cur][0];
    __builtin_amdgcn_s_setprio(1);
#pragma unroll
    for (int t = 0; t < 4; t++) {
      const unsigned short* krow = Kcur + (16 * t + r) * 128;
#pragma unroll
      for (int c = 0; c < 4; c++) {
        const bf16x8_t kf = *(const bf16x8_t*)(krow + (((4 * c + g) ^ rs) << 3));
        sc[t] = __builtin_amdgcn_mfma_f32_16x16x32_bf16(kf, qf[c], sc[t], 0, 0, 0);
      }
    }
    __builtin_amdgcn_s_setprio(0);

    if (s == pj || s == 32) {  // last stage of current tile: causal mask
#pragma unroll
      for (int t = 0; t < 4; t++)
#pragma unroll
        for (int jj = 0; jj < 4; jj++)
          if (t * 16 + 4 * g + jj > wid * 16 + r) sc[t][jj] = -1e30f;
    }
    float lm = sc[0][0];
#pragma unroll
    for (int t = 0; t < 4; t++)
#pragma unroll
      for (int jj = 0; jj < 4; jj++) lm = fmaxf(lm, sc[t][jj]);
    if (!__all(lm <= m + 8.f)) {  // rare rescale path
      float pm = lm;
      pm = fmaxf(pm, __shfl_xor(pm, 16));
      pm = fmaxf(pm, __shfl_xor(pm, 32));
      const float mnew = fmaxf(m, pm);
      const float alpha = __expf(m - mnew);
      lsum *= alpha;
      float aj[4];
#pragma unroll
      for (int jj = 0; jj < 4; jj++) aj[jj] = __shfl(alpha, 4 * g + jj);
#pragma unroll
      for (int dt = 0; dt < 8; dt++) {
        o[dt][0] *= aj[0]; o[dt][1] *= aj[1]; o[dt][2] *= aj[2]; o[dt][3] *= aj[3];
      }
      m = mnew;
    }
    float p[16];
#pragma unroll
    for (int t = 0; t < 4; t++)
#pragma unroll
      for (int jj = 0; jj < 4; jj++) p[4 * t + jj] = __expf(sc[t][jj] - m);
    float ls = 0.f;
#pragma unroll
    for (int i = 0; i < 16; i++) ls += p[i];
    lsum += ls;

    asm volatile("" ::: "memory");
#pragma unroll
    for (int t = 0; t < 4; t++) {
      uint2 w = {pack2bf(p[4 * t], p[4 * t + 1]), pack2bf(p[4 * t + 2], p[4 * t + 3])};
      *(uint2*)(pw + r * 128 + (((2 * t + (g >> 1)) ^ rs) << 4) + ((g & 1) << 3)) = w;
    }
    asm volatile("s_waitcnt lgkmcnt(0)" ::: "memory");
    const bf16x8_t pa0 = *(const bf16x8_t*)(pw + r * 128 + ((g ^ rs) << 4));
    const bf16x8_t pa1 = *(const bf16x8_t*)(pw + r * 128 + (((4 + g) ^ rs) << 4));
    __builtin_amdgcn_s_setprio(1);
#pragma unroll
    for (int dt = 0; dt < 8; dt++)
      o[dt] = __builtin_amdgcn_mfma_f32_16x16x32_bf16(pa0, vf[dt], o[dt], 0, 0, 0);
#pragma unroll
    for (int dt = 0; dt < 8; dt++)
      o[dt] = __builtin_amdgcn_mfma_f32_16x16x32_bf16(pa1, vf[8 + dt], o[dt], 0, 0, 0);
    __builtin_amdgcn_s_setprio(0);

    // drain staging + sync before next stage overwrites / reads buffers
    asm volatile("s_waitcnt vmcnt(0)" ::: "memory");
    __builtin_amdgcn_s_barrier();
  }
  // epilogue: flush tile B
  {
    float lt = lsum;
    lt += __shfl_xor(lt, 16);
    lt += __shfl_xor(lt, 32);
    float rl[4];
#pragma unroll
    for (int jj = 0; jj < 4; jj++) rl[jj] = 1.0f / __shfl(lt, 4 * g + jj);
    unsigned short* aop = ao + ((long)(b * 2048 + tile * 64 + wid * 16 + 4 * g)) * 2048 + h * 128 + r;
#pragma unroll
    for (int dt = 0; dt < 8; dt++)
#pragma unroll
      for (int jj = 0; jj < 4; jj++)
        aop[(long)jj * 2048 + dt * 16] = f2bf(o[dt][jj] * rl[jj]);
  }
}

extern "C" void kernel_launch(void* const* d_in, const int* in_sizes, int n_in,
                              void* d_out, int out_size, void* d_ws, size_t ws_size,
                              hipStream_t stream) {
  const float* x    = (const float*)d_in[0];
  const float* sinp = (const float*)d_in[1];
  const float* cosp = (const float*)d_in[2];
  const float* Wqkv = (const float*)d_in[3];
  const float* Wo   = (const float*)d_in[4];
  float* out = (float*)d_out;
  char* ws = (char*)d_ws;

  const int B = 2, T = 2048, D = 2048, H = 16, HD = 128;
  const int M = B * T;        // 4096
  const int NQ = D + 2 * HD;  // 2304

  unsigned short* xb    = (unsigned short*)(ws + 0);         // 16,777,216
  unsigned short* wqkvT = (unsigned short*)(ws + 16777216);  //  9,437,184
  unsigned short* woT   = (unsigned short*)(ws + 26214400);  //  8,388,608
  float*          qkv   = (float*)         (ws + 34603008);  // 37,748,736
  unsigned short* qr    = (unsigned short*)(ws + 72351744);  // 16,777,216
  unsigned short* kr    = (unsigned short*)(ws + 89128960);  //  1,048,576
  unsigned short* vT    = (unsigned short*)(ws + 90177536);  //  1,048,576
  unsigned short* ao    = xb;  // reuse xb after first GEMM

  dim3 tb(64, 4);
  cvt_bf16_kernel<<<(M * D) / 1024, 256, 0, stream>>>(x, xb);
  transpose_f32_bf16<<<dim3(NQ / 64, D / 64, 1), tb, 0, stream>>>(Wqkv, wqkvT, NQ, D, 0, 0);
  transpose_f32_bf16<<<dim3(D / 64, D / 64, 1), tb, 0, stream>>>(Wo, woT, D, D, 0, 0);
  gemm_bt<<<dim3(NQ / 128, M / 128), 256, 0, stream>>>(xb, wqkvT, qkv, M, NQ, D);
  rope_kernel<<<M, 256, 0, stream>>>(qkv, sinp, cosp, qr, kr);
  transpose_f32_bf16<<<dim3(HD / 64, T / 64, B), tb, 0, stream>>>(
      qkv + 2176, vT, NQ, T, (long)T * NQ, (long)HD * T);
  mqa_attn<<<dim3(512), 256, 0, stream>>>(qr, kr, vT, ao);
  gemm_bt<<<dim3(D / 128, M / 128), 256, 0, stream>>>(ao, woT, out, M, D, D);
}

// Round 5
// 293.438 us; speedup vs baseline: 2.0645x; 1.0372x over previous
//
#include <hip/hip_runtime.h>
#include <stdint.h>

typedef __bf16 bf16x8_t __attribute__((ext_vector_type(8)));
typedef float f32x4_t __attribute__((ext_vector_type(4)));

#define AS1 __attribute__((address_space(1)))
#define AS3 __attribute__((address_space(3)))

static __device__ __forceinline__ unsigned short f2bf(float f) {
  union { float f; unsigned u; } a;
  a.f = f;
  unsigned r = a.u + 0x7fffu + ((a.u >> 16) & 1u);
  return (unsigned short)(r >> 16);
}

static __device__ __forceinline__ unsigned pack2bf(float lo, float hi) {
  return (unsigned)f2bf(lo) | ((unsigned)f2bf(hi) << 16);
}

// ---------- 1. fp32 -> bf16 elementwise ----------
__global__ void cvt_bf16_kernel(const float* __restrict__ in, unsigned short* __restrict__ out) {
  long i = ((long)blockIdx.x * blockDim.x + threadIdx.x) * 4;
  float4 v = *(const float4*)(in + i);
  ushort4 o;
  o.x = f2bf(v.x);
  o.y = f2bf(v.y);
  o.z = f2bf(v.z);
  o.w = f2bf(v.w);
  *(ushort4*)(out + i) = o;
}

// ---------- 2. fp32 [R][C] (row stride ld) -> bf16 [C][R] (row stride dld) ----------
__global__ void transpose_f32_bf16(const float* __restrict__ src, unsigned short* __restrict__ dst,
                                   int ld, int dld, long sbs, long dbs) {
  __shared__ float tile[64][65];
  src += (long)blockIdx.z * sbs;
  dst += (long)blockIdx.z * dbs;
  const int c0 = blockIdx.x * 64, r0 = blockIdx.y * 64;
  const int tx = threadIdx.x, ty = threadIdx.y;
#pragma unroll
  for (int j = 0; j < 64; j += 4)
    tile[ty + j][tx] = src[(long)(r0 + ty + j) * ld + (c0 + tx)];
  __syncthreads();
#pragma unroll
  for (int j = 0; j < 64; j += 4)
    dst[(long)(c0 + ty + j) * dld + (r0 + tx)] = f2bf(tile[tx][ty + j]);
}

// ---------- 3. GEMM: C[M][N] = A[M][K] * Bt[N][K]^T  (bf16 in, fp32 out) ----------
__global__ __launch_bounds__(256) void gemm_bt(const unsigned short* __restrict__ A,
                                               const unsigned short* __restrict__ Bt,
                                               float* __restrict__ C,
                                               int M, int N, int K) {
  __shared__ unsigned short As[128 * 32];
  __shared__ unsigned short Bs[128 * 32];
  const int tid = threadIdx.x;
  const int wid = tid >> 6, lane = tid & 63;
  const int r16 = lane & 15, g = lane >> 4;
  const long bm = (long)blockIdx.y * 128;
  const long bn = (long)blockIdx.x * 128;
  const int wr = (wid >> 1) * 64, wc = (wid & 1) * 64;
  f32x4_t acc[4][4];
#pragma unroll
  for (int i = 0; i < 4; i++)
#pragma unroll
    for (int j = 0; j < 4; j++) acc[i][j] = (f32x4_t){0.f, 0.f, 0.f, 0.f};

  for (int kt = 0; kt < K; kt += 32) {
#pragma unroll
    for (int i = 0; i < 2; i++) {
      const int chunk = (i * 4 + wid) * 64 + lane;
      const int row = chunk >> 2, col = (chunk & 3) * 8;
      __builtin_amdgcn_global_load_lds(
          (const AS1 void*)(A + (bm + row) * K + kt + col),
          (AS3 void*)(As + chunk * 8), 16, 0, 0);
      __builtin_amdgcn_global_load_lds(
          (const AS1 void*)(Bt + (bn + row) * K + kt + col),
          (AS3 void*)(Bs + chunk * 8), 16, 0, 0);
    }
    __syncthreads();
    bf16x8_t af[4], bfr[4];
#pragma unroll
    for (int mi = 0; mi < 4; mi++)
      af[mi] = *(const bf16x8_t*)(As + (wr + mi * 16 + r16) * 32 + g * 8);
#pragma unroll
    for (int ni = 0; ni < 4; ni++)
      bfr[ni] = *(const bf16x8_t*)(Bs + (wc + ni * 16 + r16) * 32 + g * 8);
#pragma unroll
    for (int mi = 0; mi < 4; mi++)
#pragma unroll
      for (int ni = 0; ni < 4; ni++)
        acc[mi][ni] = __builtin_amdgcn_mfma_f32_16x16x32_bf16(af[mi], bfr[ni], acc[mi][ni], 0, 0, 0);
    __syncthreads();
  }
#pragma unroll
  for (int mi = 0; mi < 4; mi++)
#pragma unroll
    for (int ni = 0; ni < 4; ni++) {
      const long rowb = bm + wr + mi * 16 + 4 * g;
      const long colb = bn + wc + ni * 16 + r16;
#pragma unroll
      for (int j = 0; j < 4; j++)
        C[(rowb + j) * N + colb] = acc[mi][ni][j];
    }
}

// ---------- 4. RoPE + scale fold + layout ----------
__global__ void rope_kernel(const float* __restrict__ qkv,
                            const float* __restrict__ sinp,
                            const float* __restrict__ cosp,
                            unsigned short* __restrict__ qr,
                            unsigned short* __restrict__ kr) {
  const int row = blockIdx.x;  // b*2048 + t
  const int b = row >> 11, t = row & 2047;
  const float* src = qkv + (long)row * 2304;
  const int tid = threadIdx.x;
  const int d = tid & 127;
  const int dp = (d + 64) & 127;
  const float c = cosp[t * 128 + d];
  const float s = sinp[t * 128 + d];
  const float sgn = (d < 64) ? -1.f : 1.f;
  for (int h = (tid >> 7); h < 16; h += 2) {
    const float x0 = src[h * 128 + d];
    const float xp = src[h * 128 + dp];
    qr[((long)((b * 16 + h) * 2048 + t)) * 128 + d] = f2bf((x0 * c + sgn * xp * s) * 0.0078125f);
  }
  if (tid < 128) {
    const float x0 = src[2048 + d];
    const float xp = src[2048 + dp];
    kr[((long)(b * 2048 + t)) * 128 + d] = f2bf(x0 * c + sgn * xp * s);
  }
}

// ---------- 5. causal MQA flash attention (v5) ----------
// v4 + vmcnt-order fix: per stage, issue [flush][V loads][SB][K staging][SB]
// so PV's vf-wait is vmcnt(4) (staging stays in flight) instead of vmcnt(0)
// (which drained the 16KB K-staging L2 round-trip mid-stage, serializing it).
__global__ __launch_bounds__(256, 2)
void mqa_attn(const unsigned short* __restrict__ qr,
              const unsigned short* __restrict__ kr,
              const unsigned short* __restrict__ vT,
              unsigned short* __restrict__ ao) {
  __shared__ unsigned short Kb[2][64 * 128];   // 2 x 16KB K tiles
  __shared__ unsigned short plds[4][16 * 64];  // per-wave P tile (2KB each)
  const int idx = blockIdx.x;  // 512 blocks
  const int pj = idx & 15, h = (idx >> 4) & 15, b = idx >> 8;
  const int tid = threadIdx.x;
  const int wid = tid >> 6, lane = tid & 63;
  const int r = lane & 15, g = lane >> 4;
  const int rs = r & 7;
  char* pw = (char*)&plds[wid][0];

  const unsigned short* kbase = kr + (long)b * 2048 * 128;
  const unsigned short* vbr = vT + (long)b * 128 * 2048 + (long)r * 2048 + g * 8;
  const unsigned short* qh = qr + (long)(b * 16 + h) * 2048 * 128;

  const int scol = (tid & 15) ^ ((tid >> 4) & 7);  // pre-swizzled source col

  f32x4_t o[8];
#pragma unroll
  for (int i = 0; i < 8; i++) o[i] = (f32x4_t){0.f, 0.f, 0.f, 0.f};
  float m = 0.f, lsum = 0.f;

  int tile = pj;
  bf16x8_t qf[4];
  {
    const unsigned short* qp = qh + (long)(tile * 64 + wid * 16 + r) * 128 + g * 8;
#pragma unroll
    for (int c = 0; c < 4; c++) qf[c] = *(const bf16x8_t*)(qp + c * 32);
  }

  // prologue: stage kv-block 0 into buf 0
#pragma unroll
  for (int i = 0; i < 4; i++) {
    const int row = i * 16 + (tid >> 4);
    __builtin_amdgcn_global_load_lds(
        (const AS1 void*)(kbase + (long)row * 128 + scol * 8),
        (AS3 void*)(&Kb[0][(i * 256 + tid) * 8]), 16, 0, 0);
  }
  asm volatile("s_waitcnt vmcnt(0)" ::: "memory");
  __builtin_amdgcn_s_barrier();

  const int switch_s = pj + 1;
  for (int s = 0; s <= 32; s++) {
    const int cur = s & 1;
    const int kv0 = (s <= pj) ? 64 * s : 64 * (s - 1 - pj);

    // 0. tile switch: flush tile A (O stores + Q reload) BEFORE any vmem this
    //    stage so its stores never sit between V loads and their consumers
    if (s == switch_s) {
      float lt = lsum;
      lt += __shfl_xor(lt, 16);
      lt += __shfl_xor(lt, 32);
      float rl[4];
#pragma unroll
      for (int jj = 0; jj < 4; jj++) rl[jj] = 1.0f / __shfl(lt, 4 * g + jj);
      unsigned short* aop = ao + ((long)(b * 2048 + tile * 64 + wid * 16 + 4 * g)) * 2048 + h * 128 + r;
#pragma unroll
      for (int dt = 0; dt < 8; dt++)
#pragma unroll
        for (int jj = 0; jj < 4; jj++)
          aop[(long)jj * 2048 + dt * 16] = f2bf(o[dt][jj] * rl[jj]);
      tile = 31 - pj;
      const unsigned short* qp = qh + (long)(tile * 64 + wid * 16 + r) * 128 + g * 8;
#pragma unroll
      for (int c = 0; c < 4; c++) qf[c] = *(const bf16x8_t*)(qp + c * 32);
#pragma unroll
      for (int i = 0; i < 8; i++) o[i] = (f32x4_t){0.f, 0.f, 0.f, 0.f};
      m = 0.f;
      lsum = 0.f;
    }

    // 1. V loads for THIS stage (consumed by PV below; wait will be vmcnt(4))
    bf16x8_t vf[16];
#pragma unroll
    for (int dt = 0; dt < 8; dt++) {
      vf[dt] = *(const bf16x8_t*)(vbr + (long)dt * 16 * 2048 + kv0);
      vf[8 + dt] = *(const bf16x8_t*)(vbr + (long)dt * 16 * 2048 + kv0 + 32);
    }
    __builtin_amdgcn_sched_barrier(0);

    // 2. async staging of NEXT kv tile (issued after V -> never blocks vf wait)
    if (s < 32) {
      const int kvn = (s + 1 <= pj) ? 64 * (s + 1) : 64 * (s - pj);
#pragma unroll
      for (int i = 0; i < 4; i++) {
        const int row = i * 16 + (tid >> 4);
        __builtin_amdgcn_global_load_lds(
            (const AS1 void*)(kbase + (long)(kvn + row) * 128 + scol * 8),
            (AS3 void*)(&Kb[cur ^ 1][(i * 256 + tid) * 8]), 16, 0, 0);
      }
    }
    __builtin_amdgcn_sched_barrier(0);

    // 3. QK^T from LDS K tile
    f32x4_t sc[4];
#pragma unroll
    for (int t = 0; t < 4; t++) sc[t] = (f32x4_t){0.f, 0.f, 0.f, 0.f};
    const unsigned short* Kcur = &Kb[cur][0];
    __builtin_amdgcn_s_setprio(1);
#pragma unroll
    for (int t = 0; t < 4; t++) {
      const unsigned short* krow = Kcur + (16 * t + r) * 128;
#pragma unroll
      for (int c = 0; c < 4; c++) {
        const bf16x8_t kf = *(const bf16x8_t*)(krow + (((4 * c + g) ^ rs) << 3));
        sc[t] = __builtin_amdgcn_mfma_f32_16x16x32_bf16(kf, qf[c], sc[t], 0, 0, 0);
      }
    }
    __builtin_amdgcn_s_setprio(0);

    // 4. causal mask on the current tile's last stage
    if (s == pj || s == 32) {
#pragma unroll
      for (int t = 0; t < 4; t++)
#pragma unroll
        for (int jj = 0; jj < 4; jj++)
          if (t * 16 + 4 * g + jj > wid * 16 + r) sc[t][jj] = -1e30f;
    }
    // 5. softmax (defer-max fast path)
    float lm = sc[0][0];
#pragma unroll
    for (int t = 0; t < 4; t++)
#pragma unroll
      for (int jj = 0; jj < 4; jj++) lm = fmaxf(lm, sc[t][jj]);
    if (!__all(lm <= m + 8.f)) {  // rare rescale path
      float pm = lm;
      pm = fmaxf(pm, __shfl_xor(pm, 16));
      pm = fmaxf(pm, __shfl_xor(pm, 32));
      const float mnew = fmaxf(m, pm);
      const float alpha = __expf(m - mnew);
      lsum *= alpha;
      float aj[4];
#pragma unroll
      for (int jj = 0; jj < 4; jj++) aj[jj] = __shfl(alpha, 4 * g + jj);
#pragma unroll
      for (int dt = 0; dt < 8; dt++) {
        o[dt][0] *= aj[0]; o[dt][1] *= aj[1]; o[dt][2] *= aj[2]; o[dt][3] *= aj[3];
      }
      m = mnew;
    }
    float p[16];
#pragma unroll
    for (int t = 0; t < 4; t++)
#pragma unroll
      for (int jj = 0; jj < 4; jj++) p[4 * t + jj] = __expf(sc[t][jj] - m);
    float ls = 0.f;
#pragma unroll
    for (int i = 0; i < 16; i++) ls += p[i];
    lsum += ls;

    // 6. P redistribute through per-wave LDS tile
    asm volatile("" ::: "memory");
#pragma unroll
    for (int t = 0; t < 4; t++) {
      uint2 w = {pack2bf(p[4 * t], p[4 * t + 1]), pack2bf(p[4 * t + 2], p[4 * t + 3])};
      *(uint2*)(pw + r * 128 + (((2 * t + (g >> 1)) ^ rs) << 4) + ((g & 1) << 3)) = w;
    }
    asm volatile("s_waitcnt lgkmcnt(0)" ::: "memory");
    const bf16x8_t pa0 = *(const bf16x8_t*)(pw + r * 128 + ((g ^ rs) << 4));
    const bf16x8_t pa1 = *(const bf16x8_t*)(pw + r * 128 + (((4 + g) ^ rs) << 4));

    // 7. PV (vf wait here is vmcnt(4): staging still in flight)
    __builtin_amdgcn_s_setprio(1);
#pragma unroll
    for (int dt = 0; dt < 8; dt++)
      o[dt] = __builtin_amdgcn_mfma_f32_16x16x32_bf16(pa0, vf[dt], o[dt], 0, 0, 0);
#pragma unroll
    for (int dt = 0; dt < 8; dt++)
      o[dt] = __builtin_amdgcn_mfma_f32_16x16x32_bf16(pa1, vf[8 + dt], o[dt], 0, 0, 0);
    __builtin_amdgcn_s_setprio(0);

    // 8. drain staging + sync (staging had the whole stage body to complete)
    asm volatile("s_waitcnt vmcnt(0)" ::: "memory");
    __builtin_amdgcn_s_barrier();
  }
  // epilogue: flush tile B
  {
    float lt = lsum;
    lt += __shfl_xor(lt, 16);
    lt += __shfl_xor(lt, 32);
    float rl[4];
#pragma unroll
    for (int jj = 0; jj < 4; jj++) rl[jj] = 1.0f / __shfl(lt, 4 * g + jj);
    unsigned short* aop = ao + ((long)(b * 2048 + tile * 64 + wid * 16 + 4 * g)) * 2048 + h * 128 + r;
#pragma unroll
    for (int dt = 0; dt < 8; dt++)
#pragma unroll
      for (int jj = 0; jj < 4; jj++)
        aop[(long)jj * 2048 + dt * 16] = f2bf(o[dt][jj] * rl[jj]);
  }
}

extern "C" void kernel_launch(void* const* d_in, const int* in_sizes, int n_in,
                              void* d_out, int out_size, void* d_ws, size_t ws_size,
                              hipStream_t stream) {
  const float* x    = (const float*)d_in[0];
  const float* sinp = (const float*)d_in[1];
  const float* cosp = (const float*)d_in[2];
  const float* Wqkv = (const float*)d_in[3];
  const float* Wo   = (const float*)d_in[4];
  float* out = (float*)d_out;
  char* ws = (char*)d_ws;

  const int B = 2, T = 2048, D = 2048, H = 16, HD = 128;
  const int M = B * T;        // 4096
  const int NQ = D + 2 * HD;  // 2304

  unsigned short* xb    = (unsigned short*)(ws + 0);         // 16,777,216
  unsigned short* wqkvT = (unsigned short*)(ws + 16777216);  //  9,437,184
  unsigned short* woT   = (unsigned short*)(ws + 26214400);  //  8,388,608
  float*          qkv   = (float*)         (ws + 34603008);  // 37,748,736
  unsigned short* qr    = (unsigned short*)(ws + 72351744);  // 16,777,216
  unsigned short* kr    = (unsigned short*)(ws + 89128960);  //  1,048,576
  unsigned short* vT    = (unsigned short*)(ws + 90177536);  //  1,048,576
  unsigned short* ao    = xb;  // reuse xb after first GEMM

  dim3 tb(64, 4);
  cvt_bf16_kernel<<<(M * D) / 1024, 256, 0, stream>>>(x, xb);
  transpose_f32_bf16<<<dim3(NQ / 64, D / 64, 1), tb, 0, stream>>>(Wqkv, wqkvT, NQ, D, 0, 0);
  transpose_f32_bf16<<<dim3(D / 64, D / 64, 1), tb, 0, stream>>>(Wo, woT, D, D, 0, 0);
  gemm_bt<<<dim3(NQ / 128, M / 128), 256, 0, stream>>>(xb, wqkvT, qkv, M, NQ, D);
  rope_kernel<<<M, 256, 0, stream>>>(qkv, sinp, cosp, qr, kr);
  transpose_f32_bf16<<<dim3(HD / 64, T / 64, B), tb, 0, stream>>>(
      qkv + 2176, vT, NQ, T, (long)T * NQ, (long)HD * T);
  mqa_attn<<<dim3(512), 256, 0, stream>>>(qr, kr, vT, ao);
  gemm_bt<<<dim3(D / 128, M / 128), 256, 0, stream>>>(ao, woT, out, M, D, D);
}